// Round 1
// baseline (3812.039 us; speedup 1.0000x reference)
//
#include <hip/hip_runtime.h>
#include <hip/hip_bf16.h>
#include <math.h>

// Problem constants (from reference setup_inputs)
#define TT 64
#define BB 1024
#define SS 256
#define AA 16
#define HH 32
#define RR 32
#define EPSF 1e-6f

// ---------------------------------------------------------------------------
// Phase 0a: trans logits + softmax.
// trans[k,i,j] = softmax_j( sum_r pu[r,i]*pv[r,j]*pw[r,k] )
// stored as TC2[i][j*16+k]  (row = i (GEMM K-dim), col c = j*16+k) so the
// step-GEMM block (128 consecutive c) covers all 16 k of 8 j's -> fused k-sum.
// ---------------------------------------------------------------------------
__global__ __launch_bounds__(256) void k_trans(
    const float* __restrict__ pu, const float* __restrict__ pv,
    const float* __restrict__ pw, float* __restrict__ TC2)
{
  const int bid = blockIdx.x;          // k*256 + i
  const int k = bid >> 8;
  const int i = bid & 255;
  const int j = threadIdx.x;
  float acc = 0.f;
  #pragma unroll
  for (int r = 0; r < RR; ++r)
    acc += pu[r*SS + i] * pv[r*SS + j] * pw[r*AA + k];

  const int lane = j & 63, wid = j >> 6;
  __shared__ float wred[4];
  float m = acc;
  #pragma unroll
  for (int off = 1; off < 64; off <<= 1) m = fmaxf(m, __shfl_xor(m, off));
  if (lane == 0) wred[wid] = m;
  __syncthreads();
  m = fmaxf(fmaxf(wred[0], wred[1]), fmaxf(wred[2], wred[3]));
  float p = expf(acc - m);
  float s = p;
  #pragma unroll
  for (int off = 1; off < 64; off <<= 1) s += __shfl_xor(s, off);
  __syncthreads();
  if (lane == 0) wred[wid] = s;
  __syncthreads();
  s = wred[0] + wred[1] + wred[2] + wred[3];
  TC2[i*4096 + j*16 + k] = p / s;
}

// ---------------------------------------------------------------------------
// Phase 0b: truncated Poisson pdf over k=1..32 for scalar tau.
// ---------------------------------------------------------------------------
__global__ void k_tau(const float* __restrict__ tau_param, float* __restrict__ taupdf)
{
  const int tid = threadIdx.x;   // 64 threads, one wave
  float tp = tau_param[0];
  tp = fminf(fmaxf(tp, logf(1e-6f)), logf(1000.f));
  const float tau = expf(tp);
  float lp = -1e30f;
  if (tid < HH) {
    float kf = (float)(tid + 1);
    lp = kf * logf(tau) - tau - lgammaf(kf + 1.f);
  }
  float m = lp;
  #pragma unroll
  for (int off = 1; off < 64; off <<= 1) m = fmaxf(m, __shfl_xor(m, off));
  float p = (tid < HH) ? expf(lp - m) : 0.f;
  float s = p;
  #pragma unroll
  for (int off = 1; off < 64; off <<= 1) s += __shfl_xor(s, off);
  if (tid < HH) taupdf[tid] = p / s;
}

// ---------------------------------------------------------------------------
// Phase 1 step GEMM (fp32):  Y[n][c] = sum_i bel[n][i]*TC2[i][c],  c=j*16+k
// then fused in-block:       Sn[n][j] = sum_k u[n][k] * Y[n][j*16+k]
// Tiles: BM=64 rows(n), BN=128 cols(c), BK=64 (i). 256 thr, thread tile 8x4.
// grid (16,32) = 512 blocks -> 2 blocks/CU, 8 waves/CU.
// A staged transposed in LDS (b128 frag, wave-broadcast); B streamed from
// L2-resident TC2 (4 MB = one XCD L2).
// ---------------------------------------------------------------------------
__global__ __launch_bounds__(256) void k_step_gemm(
    const float* __restrict__ bel,   // [1024][256]
    const float* __restrict__ TC2,   // [256][4096]
    const float* __restrict__ u_t,   // [1024][16]
    float* __restrict__ Sn)          // [1024][256]
{
  __shared__ float As[64][68];       // [i_local][n_local], pad 68 (16B-aligned frags)
  __shared__ float Ul[64][17];       // u tile
  const int tid = threadIdx.x;
  const int ty = tid >> 5;           // 0..7  -> rows ty*8..+7
  const int tx = tid & 31;           // 0..31 -> cols tx*4..+3
  const int n0 = blockIdx.x * 64;
  const int c0 = blockIdx.y * 128;

  { // stage u: 64 rows x 16
    int r = tid >> 2, c4 = tid & 3;
    float4 v = *(const float4*)&u_t[(n0 + r)*AA + c4*4];
    Ul[r][c4*4+0] = v.x; Ul[r][c4*4+1] = v.y; Ul[r][c4*4+2] = v.z; Ul[r][c4*4+3] = v.w;
  }

  float acc[8][4] = {};
  for (int k0 = 0; k0 < 256; k0 += 64) {
    __syncthreads();
    #pragma unroll
    for (int l = 0; l < 4; ++l) {   // stage A chunk 64x64 transposed
      int idx = l*256 + tid;
      int r = idx >> 4;             // 0..63 (n row)
      int c4 = idx & 15;            // f4 index along i
      float4 v = *(const float4*)&bel[(n0 + r)*SS + k0 + c4*4];
      As[c4*4+0][r] = v.x; As[c4*4+1][r] = v.y; As[c4*4+2][r] = v.z; As[c4*4+3][r] = v.w;
    }
    __syncthreads();
    #pragma unroll 4
    for (int kk = 0; kk < 64; ++kk) {
      float4 bfr = *(const float4*)&TC2[(size_t)(k0+kk)*4096 + c0 + tx*4];
      float4 a0 = *(const float4*)&As[kk][ty*8];
      float4 a1 = *(const float4*)&As[kk][ty*8+4];
      float av[8] = {a0.x,a0.y,a0.z,a0.w,a1.x,a1.y,a1.z,a1.w};
      float bv[4] = {bfr.x,bfr.y,bfr.z,bfr.w};
      #pragma unroll
      for (int rr = 0; rr < 8; ++rr)
        #pragma unroll
        for (int cc = 0; cc < 4; ++cc)
          acc[rr][cc] += av[rr] * bv[cc];
    }
  }

  // fused k-reduction: c_local = tx*4+cc -> j_local = tx>>2, k = (tx&3)*4+cc
  const int klo = (tx & 3) * 4;
  const int jl  = tx >> 2;
  #pragma unroll
  for (int rr = 0; rr < 8; ++rr) {
    float part = 0.f;
    #pragma unroll
    for (int cc = 0; cc < 4; ++cc)
      part += acc[rr][cc] * Ul[ty*8+rr][klo+cc];
    part += __shfl_xor(part, 1);
    part += __shfl_xor(part, 2);
    if ((tx & 3) == 0)
      Sn[(size_t)(n0 + ty*8 + rr)*SS + blockIdx.y*8 + jl] = part;
  }
}

// ---------------------------------------------------------------------------
// Phase 1 softmax: b_post[n][j] = softmax_j( log(s_next+eps) + logp_o[t][n][j] )
// one wave per row n; grid 256 x 256 thr.
// ---------------------------------------------------------------------------
__global__ __launch_bounds__(256) void k_step_softmax(
    const float* __restrict__ Sn, const float* __restrict__ lo_t,
    float* __restrict__ bpost)
{
  const int tid = threadIdx.x;
  const int wid = tid >> 6, lane = tid & 63;
  const int n = blockIdx.x * 4 + wid;
  float4 s4 = *(const float4*)&Sn[(size_t)n*SS + lane*4];
  float4 l4 = *(const float4*)&lo_t[(size_t)n*SS + lane*4];
  float lg[4] = { logf(s4.x + EPSF) + l4.x, logf(s4.y + EPSF) + l4.y,
                  logf(s4.z + EPSF) + l4.z, logf(s4.w + EPSF) + l4.w };
  float m = fmaxf(fmaxf(lg[0], lg[1]), fmaxf(lg[2], lg[3]));
  #pragma unroll
  for (int off = 1; off < 64; off <<= 1) m = fmaxf(m, __shfl_xor(m, off));
  float p[4], s = 0.f;
  #pragma unroll
  for (int c = 0; c < 4; ++c) { p[c] = expf(lg[c] - m); s += p[c]; }
  #pragma unroll
  for (int off = 1; off < 64; off <<= 1) s += __shfl_xor(s, off);
  const float inv = 1.0f / s;
  float4 o = { p[0]*inv, p[1]*inv, p[2]*inv, p[3]*inv };
  *(float4*)&bpost[(size_t)n*SS + lane*4] = o;
}

// ---------------------------------------------------------------------------
// Phase 2: for each (n, t-half): P[hk][t] = sum_i value[h,n,k,i]*b_post[t,n,i]
// softmax over k (16, via shfl_xor(4)), weight tau_pdf[h], tree-reduce over h,
// write alpha_pi[t][n][k]. value read exactly once (512 MB total).
// 256 thr: ty=tid>>2 (rows hk=ty*8..+7), tx=tid&3 (t=tx*8..+7 local).
// V tile in LDS, columns swizzled with group stride 12 (2-way conflicts).
// b_post fragments read straight from global (L2/L3-resident, lane-dedup'd).
// ---------------------------------------------------------------------------
__global__ __launch_bounds__(256) void k_phase2(
    const float* __restrict__ value,   // [32][1024][16][256]
    const float* __restrict__ alphab,  // [64][1024][256]
    const float* __restrict__ taupdf,  // [32]
    float* __restrict__ alphapi)       // [64][1024][16]
{
  const int tid = threadIdx.x;
  const int ty = tid >> 2;             // 0..63
  const int tx = tid & 3;              // 0..3
  const int n  = blockIdx.x >> 1;
  const int t0 = (blockIdx.x & 1) * 32;
  __shared__ float Vl[16*772];         // [i_local 16][swizzled col, stride 772]

  float acc[8][8] = {};
  for (int i0 = 0; i0 < 256; i0 += 16) {
    __syncthreads();
    #pragma unroll
    for (int l = 0; l < 8; ++l) {     // stage V chunk: 512 rows x 16 i
      int idx = l*256 + tid;
      int r  = idx >> 2;               // hk row 0..511
      int c4 = idx & 3;
      int h = r >> 4, kk = r & 15;
      float4 v = *(const float4*)&value[(((size_t)h*BB + n)*AA + kk)*SS + i0 + c4*4];
      int colb = (r >> 3)*12 + (r & 7);   // swizzle: 8-row groups at stride 12
      Vl[(c4*4+0)*772 + colb] = v.x;
      Vl[(c4*4+1)*772 + colb] = v.y;
      Vl[(c4*4+2)*772 + colb] = v.z;
      Vl[(c4*4+3)*772 + colb] = v.w;
    }
    __syncthreads();
    #pragma unroll
    for (int i4 = 0; i4 < 16; i4 += 4) {
      float4 bf[8];
      #pragma unroll
      for (int r = 0; r < 8; ++r)      // b_post frags for 8 t, 4 i (lane-dedup'd)
        bf[r] = *(const float4*)&alphab[(size_t)(t0 + tx*8 + r)*(BB*SS) + (size_t)n*SS + i0 + i4];
      #pragma unroll
      for (int q = 0; q < 4; ++q) {
        const int ii = i4 + q;
        const float* vrow = &Vl[ii*772 + ty*12];
        float4 a0 = *(const float4*)&vrow[0];
        float4 a1 = *(const float4*)&vrow[4];
        float av[8] = {a0.x,a0.y,a0.z,a0.w,a1.x,a1.y,a1.z,a1.w};
        float bv[8];
        #pragma unroll
        for (int cc = 0; cc < 8; ++cc)
          bv[cc] = (q==0) ? bf[cc].x : (q==1) ? bf[cc].y : (q==2) ? bf[cc].z : bf[cc].w;
        #pragma unroll
        for (int rr = 0; rr < 8; ++rr)
          #pragma unroll
          for (int cc = 0; cc < 8; ++cc)
            acc[rr][cc] += av[rr] * bv[cc];
      }
    }
  }

  // softmax over k (rows hk = ty*8..+7: h = ty>>1, k-range (ty&1)*8..+7;
  // partner half at lane^4), then tau weighting.
  const int h = ty >> 1;
  const int kbase = (ty & 1) * 8;
  const float tw = taupdf[h];
  #pragma unroll
  for (int cc = 0; cc < 8; ++cc) {
    float m = acc[0][cc];
    #pragma unroll
    for (int rr = 1; rr < 8; ++rr) m = fmaxf(m, acc[rr][cc]);
    m = fmaxf(m, __shfl_xor(m, 4));
    float s = 0.f;
    #pragma unroll
    for (int rr = 0; rr < 8; ++rr) { float e = __expf(acc[rr][cc] - m); acc[rr][cc] = e; s += e; }
    s += __shfl_xor(s, 4);
    const float w = tw / s;
    #pragma unroll
    for (int rr = 0; rr < 8; ++rr) acc[rr][cc] *= w;
  }

  // tree-reduce over h (32 groups) through LDS (reuse Vl), then h==0 writes.
  float* red = Vl;                      // needs 256*32 floats = 8192 <= 12352
  #pragma unroll
  for (int half = 16; half >= 1; half >>= 1) {
    __syncthreads();
    if (h >= half && h < 2*half) {
      const int rb = (h - half)*16 + kbase;
      #pragma unroll
      for (int rr = 0; rr < 8; ++rr) {
        float4 w0 = { acc[rr][0], acc[rr][1], acc[rr][2], acc[rr][3] };
        float4 w1 = { acc[rr][4], acc[rr][5], acc[rr][6], acc[rr][7] };
        *(float4*)&red[(rb + rr)*32 + tx*8]     = w0;
        *(float4*)&red[(rb + rr)*32 + tx*8 + 4] = w1;
      }
    }
    __syncthreads();
    if (h < half) {
      const int rb = h*16 + kbase;
      #pragma unroll
      for (int rr = 0; rr < 8; ++rr) {
        float4 r0 = *(const float4*)&red[(rb + rr)*32 + tx*8];
        float4 r1 = *(const float4*)&red[(rb + rr)*32 + tx*8 + 4];
        acc[rr][0] += r0.x; acc[rr][1] += r0.y; acc[rr][2] += r0.z; acc[rr][3] += r0.w;
        acc[rr][4] += r1.x; acc[rr][5] += r1.y; acc[rr][6] += r1.z; acc[rr][7] += r1.w;
      }
    }
  }
  if (h == 0) {
    #pragma unroll
    for (int cc = 0; cc < 8; ++cc)
      #pragma unroll
      for (int rr = 0; rr < 8; ++rr)
        alphapi[(size_t)(t0 + tx*8 + cc)*(BB*AA) + (size_t)n*AA + kbase + rr] = acc[rr][cc];
  }
}

// ---------------------------------------------------------------------------
extern "C" void kernel_launch(void* const* d_in, const int* in_sizes, int n_in,
                              void* d_out, int out_size, void* d_ws, size_t ws_size,
                              hipStream_t stream) {
  const float* logp_o = (const float*)d_in[0];   // [64][1024][256]
  const float* u      = (const float*)d_in[1];   // [64][1024][16]
  const float* value  = (const float*)d_in[2];   // [32][1024][16][256]
  const float* b      = (const float*)d_in[3];   // [1024][256]
  const float* tau_p  = (const float*)d_in[4];   // [1][1]
  const float* pu     = (const float*)d_in[5];   // [1][32][256]
  const float* pv     = (const float*)d_in[6];   // [1][32][256]
  const float* pw     = (const float*)d_in[7];   // [1][32][16]

  float* alphab  = (float*)d_out;                         // [64][1024][256]
  float* alphapi = (float*)d_out + (size_t)TT*BB*SS;      // [64][1024][16]

  float* TC2    = (float*)d_ws;                    // 256*4096 = 1M floats
  float* Sn     = TC2 + (size_t)SS*AA*SS;          // 1024*256
  float* taupdf = Sn + (size_t)BB*SS;              // 32

  k_trans<<<AA*SS, 256, 0, stream>>>(pu, pv, pw, TC2);
  k_tau<<<1, 64, 0, stream>>>(tau_p, taupdf);

  for (int t = 0; t < TT; ++t) {
    const float* bel = (t == 0) ? b : (alphab + (size_t)(t-1)*BB*SS);
    k_step_gemm<<<dim3(16,32), 256, 0, stream>>>(bel, TC2, u + (size_t)t*BB*AA, Sn);
    k_step_softmax<<<256, 256, 0, stream>>>(Sn, logp_o + (size_t)t*BB*SS,
                                            alphab + (size_t)t*BB*SS);
  }
  k_phase2<<<2048, 256, 0, stream>>>(value, alphab, taupdf, alphapi);
}

// Round 4
// 1794.656 us; speedup vs baseline: 2.1241x; 2.1241x over previous
//
#include <hip/hip_runtime.h>
#include <hip/hip_bf16.h>
#include <math.h>

#define TT 64
#define BB 1024
#define SS 256
#define AA 16
#define HH 32
#define RR 32
#define EPSF 1e-6f

typedef unsigned short ushortT;
typedef __attribute__((ext_vector_type(8))) short bf16x8;
typedef __attribute__((ext_vector_type(4))) float f32x4;

// global_load_lds: 16B per lane, LDS dest = wave-uniform base + lane*16.
#define GLD16(g, l) __builtin_amdgcn_global_load_lds( \
    (const __attribute__((address_space(1))) unsigned int*)(g), \
    (__attribute__((address_space(3))) unsigned int*)(l), 16, 0, 0)

__device__ __forceinline__ ushortT f2bf(float x) {
  __hip_bfloat16 h = __float2bfloat16(x);
  return *reinterpret_cast<ushortT*>(&h);
}

// ---------------------------------------------------------------------------
// Phase 0a: trans logits + softmax over j; write bf16 TC2T[c=j*16+k][i]
// (B^T layout for the MFMA GEMM: row c, contiguous i).
// ---------------------------------------------------------------------------
__global__ __launch_bounds__(256) void k_trans(
    const float* __restrict__ pu, const float* __restrict__ pv,
    const float* __restrict__ pw, ushortT* __restrict__ tct)
{
  const int bid = blockIdx.x;          // k*256 + i
  const int k = bid >> 8;
  const int i = bid & 255;
  const int j = threadIdx.x;
  float acc = 0.f;
  #pragma unroll
  for (int r = 0; r < RR; ++r)
    acc += pu[r*SS + i] * pv[r*SS + j] * pw[r*AA + k];

  const int lane = j & 63, wid = j >> 6;
  __shared__ float wred[4];
  float m = acc;
  #pragma unroll
  for (int off = 1; off < 64; off <<= 1) m = fmaxf(m, __shfl_xor(m, off));
  if (lane == 0) wred[wid] = m;
  __syncthreads();
  m = fmaxf(fmaxf(wred[0], wred[1]), fmaxf(wred[2], wred[3]));
  float p = expf(acc - m);
  float s = p;
  #pragma unroll
  for (int off = 1; off < 64; off <<= 1) s += __shfl_xor(s, off);
  __syncthreads();
  if (lane == 0) wred[wid] = s;
  __syncthreads();
  s = wred[0] + wred[1] + wred[2] + wred[3];
  tct[((size_t)j*16 + k)*SS + i] = f2bf(p / s);
}

// ---------------------------------------------------------------------------
// Phase 0b: truncated Poisson pdf.
// ---------------------------------------------------------------------------
__global__ void k_tau(const float* __restrict__ tau_param, float* __restrict__ taupdf)
{
  const int tid = threadIdx.x;
  float tp = tau_param[0];
  tp = fminf(fmaxf(tp, logf(1e-6f)), logf(1000.f));
  const float tau = expf(tp);
  float lp = -1e30f;
  if (tid < HH) {
    float kf = (float)(tid + 1);
    lp = kf * logf(tau) - tau - lgammaf(kf + 1.f);
  }
  float m = lp;
  #pragma unroll
  for (int off = 1; off < 64; off <<= 1) m = fmaxf(m, __shfl_xor(m, off));
  float p = (tid < HH) ? expf(lp - m) : 0.f;
  float s = p;
  #pragma unroll
  for (int off = 1; off < 64; off <<= 1) s += __shfl_xor(s, off);
  if (tid < HH) taupdf[tid] = p / s;
}

// ---------------------------------------------------------------------------
// Phase 0c: b (fp32) -> bel bf16 for step 0.
// ---------------------------------------------------------------------------
__global__ __launch_bounds__(256) void k_cvt(const float* __restrict__ b,
                                             ushortT* __restrict__ belb)
{
  int idx4 = blockIdx.x*256 + threadIdx.x;    // 65536 f32x4
  f32x4 v = *(const f32x4*)&b[(size_t)idx4*4];
  ushort4 o = { f2bf(v.x), f2bf(v.y), f2bf(v.z), f2bf(v.w) };
  *(ushort4*)&belb[(size_t)idx4*4] = o;
}

// ---------------------------------------------------------------------------
// Phase 1 step GEMM (bf16 MFMA): Y[n][c]=sum_i bel[n][i]*trans[c][i], c=j*16+k
// fused epilogue: Sn[n][j] = sum_k u[n][k]*Y[n][j*16+k]  (lane shuffle-reduce)
// BM=64, BN=128, BK=64. 256 thr = 4 waves (2x2), wave tile 32x64.
// LDS linear + inverse-swizzled global src (T2-compatible with gload_lds).
// ---------------------------------------------------------------------------
__global__ __launch_bounds__(256) void k_step_gemm(
    const ushortT* __restrict__ belb,  // [1024][256] bf16
    const ushortT* __restrict__ tct,   // [4096][256] bf16
    const float* __restrict__ u_t,     // [1024][16]
    float* __restrict__ Sn)            // [1024][256]
{
  __shared__ ushortT As[64*64];    // [row][k] xor-swizzled chunks, 8KB
  __shared__ ushortT Bs[128*64];   // [col][k] xor-swizzled chunks, 16KB
  __shared__ float   Ul[64*16];    // 4KB
  const int tid = threadIdx.x;
  const int l = tid & 63, wid = tid >> 6;
  const int wr = wid >> 1, wc = wid & 1;
  const int n0 = blockIdx.x * 64;
  const int c0 = blockIdx.y * 128;

  { // stage u tile (covered by first loop barrier)
    int row = tid >> 2, q = tid & 3;
    *(f32x4*)&Ul[row*16 + q*4] = *(const f32x4*)&u_t[(size_t)(n0+row)*AA + q*4];
  }

  f32x4 acc[2][4] = {};

  for (int k0 = 0; k0 < 256; k0 += 64) {
    __syncthreads();                       // prev compute done reading LDS
    const int e = l >> 3;                  // row-in-instr 0..7
    const int ch = (l & 7) ^ e;            // inverse swizzle: key = row&7 = e
    #pragma unroll
    for (int s = 0; s < 6; ++s) {
      int q = wid*6 + s;                   // 0..23
      if (q < 8) {
        int r0 = q*8;
        GLD16(belb + (size_t)(n0 + r0 + e)*SS + k0 + ch*8, &As[r0*64]);
      } else {
        int r0 = (q-8)*8;
        GLD16(tct + (size_t)(c0 + r0 + e)*SS + k0 + ch*8, &Bs[r0*64]);
      }
    }
    __syncthreads();                       // drains vmcnt(0): tiles ready
    #pragma unroll
    for (int kf = 0; kf < 2; ++kf) {
      bf16x8 af[2], bfr[4];
      #pragma unroll
      for (int fm = 0; fm < 2; ++fm) {
        int row = wr*32 + fm*16 + (l & 15);
        int c = (kf*4 + (l >> 4)) ^ (row & 7);
        af[fm] = *(const bf16x8*)&As[row*64 + c*8];
      }
      #pragma unroll
      for (int cn = 0; cn < 4; ++cn) {
        int col = wc*64 + cn*16 + (l & 15);
        int c = (kf*4 + (l >> 4)) ^ (col & 7);
        bfr[cn] = *(const bf16x8*)&Bs[col*64 + c*8];
      }
      #pragma unroll
      for (int fm = 0; fm < 2; ++fm)
        #pragma unroll
        for (int cn = 0; cn < 4; ++cn)
          acc[fm][cn] = __builtin_amdgcn_mfma_f32_16x16x32_bf16(
              af[fm], bfr[cn], acc[fm][cn], 0, 0, 0);
    }
  }

  // epilogue: C frag lane layout col=l&15 (=action k), row=(l>>4)*4+reg
  const int ka = l & 15;
  const int lg = l >> 4;
  #pragma unroll
  for (int fm = 0; fm < 2; ++fm) {
    #pragma unroll
    for (int cn = 0; cn < 4; ++cn) {
      const int j = blockIdx.y*8 + wc*4 + cn;
      float v[4];
      #pragma unroll
      for (int r = 0; r < 4; ++r) {
        int nl = wr*32 + fm*16 + lg*4 + r;
        v[r] = acc[fm][cn][r] * Ul[nl*16 + ka];
      }
      #pragma unroll
      for (int off = 1; off < 16; off <<= 1) {
        #pragma unroll
        for (int r = 0; r < 4; ++r) v[r] += __shfl_xor(v[r], off);
      }
      if (ka == 0) {
        #pragma unroll
        for (int r = 0; r < 4; ++r) {
          int nl = wr*32 + fm*16 + lg*4 + r;
          Sn[(size_t)(n0 + nl)*SS + j] = v[r];
        }
      }
    }
  }
}

// ---------------------------------------------------------------------------
// Phase 1 softmax: b_post = softmax(log(s_next+eps)+logp_o); writes fp32 out
// and bf16 copy (next step's GEMM A operand).
// ---------------------------------------------------------------------------
__global__ __launch_bounds__(256) void k_step_softmax(
    const float* __restrict__ Sn, const float* __restrict__ lo_t,
    float* __restrict__ bpost, ushortT* __restrict__ belb)
{
  const int tid = threadIdx.x;
  const int wid = tid >> 6, lane = tid & 63;
  const int n = blockIdx.x * 4 + wid;
  float4 s4 = *(const float4*)&Sn[(size_t)n*SS + lane*4];
  float4 l4 = *(const float4*)&lo_t[(size_t)n*SS + lane*4];
  float lg[4] = { logf(s4.x + EPSF) + l4.x, logf(s4.y + EPSF) + l4.y,
                  logf(s4.z + EPSF) + l4.z, logf(s4.w + EPSF) + l4.w };
  float m = fmaxf(fmaxf(lg[0], lg[1]), fmaxf(lg[2], lg[3]));
  #pragma unroll
  for (int off = 1; off < 64; off <<= 1) m = fmaxf(m, __shfl_xor(m, off));
  float p[4], s = 0.f;
  #pragma unroll
  for (int c = 0; c < 4; ++c) { p[c] = expf(lg[c] - m); s += p[c]; }
  #pragma unroll
  for (int off = 1; off < 64; off <<= 1) s += __shfl_xor(s, off);
  const float inv = 1.0f / s;
  float4 o = { p[0]*inv, p[1]*inv, p[2]*inv, p[3]*inv };
  *(float4*)&bpost[(size_t)n*SS + lane*4] = o;
  ushort4 ob = { f2bf(o.x), f2bf(o.y), f2bf(o.z), f2bf(o.w) };
  *(ushort4*)&belb[(size_t)n*SS + lane*4] = ob;
}

// ---------------------------------------------------------------------------
// Phase 2: block = (n, h-half). value fetched exactly once.
// P[hk][t] = sum_i value[h,n,k,i]*b_post[t,n,i]; softmax over k (shfl_xor 8);
// tau-weight; tree-reduce 16 h in-block; partials to ws; combine kernel sums.
// Staging via gload_lds, double-XOR swizzle q^=(row^(row>>3))&7 (write rows
// differ in row&7, read rows differ in row>>3 -> both conflict-free).
// ---------------------------------------------------------------------------
__global__ __launch_bounds__(256) void k_phase2(
    const float* __restrict__ value,   // [32][1024][16][256]
    const float* __restrict__ alphab,  // [64][1024][256]
    const float* __restrict__ taupdf,  // [32]
    float* __restrict__ part)          // [2][1024][64*16]
{
  __shared__ float Vl[256*32];   // 32KB: [hk row][i chunk of 32]
  __shared__ float Bl[64*32];    // 8KB:  [t][i chunk of 32]
  const int tid = threadIdx.x;
  const int l = tid & 63, wid = tid >> 6;
  const int n  = blockIdx.x >> 1;
  const int hh = blockIdx.x & 1;
  const int ty = tid >> 3, tx = tid & 7;   // rows ty*8..+7 ; t = tx*8..+7

  float acc[8][8] = {};

  for (int i0 = 0; i0 < 256; i0 += 32) {
    __syncthreads();
    const int e = l >> 3;
    #pragma unroll
    for (int s = 0; s < 10; ++s) {
      int q = wid*10 + s;                  // 0..39
      if (q < 32) {
        int row = q*8 + e;
        int qg = (l & 7) ^ ((row ^ (row >> 3)) & 7);
        const float* g = value +
            ((((size_t)(hh*16 + (row >> 4)))*BB + n)*AA + (row & 15))*SS + i0 + qg*4;
        GLD16(g, &Vl[q*8*32]);
      } else {
        int t = (q-32)*8 + e;
        int qg = (l & 7) ^ ((t ^ (t >> 3)) & 7);
        const float* g = alphab + ((size_t)t*BB + n)*SS + i0 + qg*4;
        GLD16(g, &Bl[(q-32)*8*32]);
      }
    }
    __syncthreads();
    #pragma unroll
    for (int qq = 0; qq < 8; ++qq) {
      f32x4 av[8], bv[8];
      #pragma unroll
      for (int rr = 0; rr < 8; ++rr) {
        int row = ty*8 + rr;
        av[rr] = *(const f32x4*)&Vl[row*32 + ((qq ^ ((rr ^ ty) & 7)) * 4)];
      }
      #pragma unroll
      for (int cc = 0; cc < 8; ++cc) {
        int t = tx*8 + cc;
        bv[cc] = *(const f32x4*)&Bl[t*32 + ((qq ^ ((cc ^ tx) & 7)) * 4)];
      }
      #pragma unroll
      for (int ee = 0; ee < 4; ++ee)
        #pragma unroll
        for (int rr = 0; rr < 8; ++rr)
          #pragma unroll
          for (int cc = 0; cc < 8; ++cc)
            acc[rr][cc] += av[rr][ee] * bv[cc][ee];
    }
  }

  // softmax over k: local row = g*16 + (ty&1)*8 + rr, g = ty>>1; partner tid^8
  const int g = ty >> 1;
  const float tw = taupdf[hh*16 + g];
  #pragma unroll
  for (int cc = 0; cc < 8; ++cc) {
    float m = acc[0][cc];
    #pragma unroll
    for (int rr = 1; rr < 8; ++rr) m = fmaxf(m, acc[rr][cc]);
    m = fmaxf(m, __shfl_xor(m, 8));
    float s = 0.f;
    #pragma unroll
    for (int rr = 0; rr < 8; ++rr) { float ev = __expf(acc[rr][cc] - m); acc[rr][cc] = ev; s += ev; }
    s += __shfl_xor(s, 8);
    const float w = tw / s;
    #pragma unroll
    for (int rr = 0; rr < 8; ++rr) acc[rr][cc] *= w;
  }

  // tree-reduce over g (16 groups) through Vl (exactly 8192 f32 needed)
  float* red = Vl;
  #pragma unroll
  for (int half = 8; half >= 1; half >>= 1) {
    __syncthreads();
    if (g >= half && g < 2*half) {
      int rb = (g - half)*16 + (ty & 1)*8;
      #pragma unroll
      for (int rr = 0; rr < 8; ++rr) {
        f32x4 w0 = { acc[rr][0], acc[rr][1], acc[rr][2], acc[rr][3] };
        f32x4 w1 = { acc[rr][4], acc[rr][5], acc[rr][6], acc[rr][7] };
        *(f32x4*)&red[(rb + rr)*64 + tx*8]     = w0;
        *(f32x4*)&red[(rb + rr)*64 + tx*8 + 4] = w1;
      }
    }
    __syncthreads();
    if (g < half) {
      int rb = g*16 + (ty & 1)*8;
      #pragma unroll
      for (int rr = 0; rr < 8; ++rr) {
        f32x4 r0 = *(const f32x4*)&red[(rb + rr)*64 + tx*8];
        f32x4 r1 = *(const f32x4*)&red[(rb + rr)*64 + tx*8 + 4];
        acc[rr][0] += r0.x; acc[rr][1] += r0.y; acc[rr][2] += r0.z; acc[rr][3] += r0.w;
        acc[rr][4] += r1.x; acc[rr][5] += r1.y; acc[rr][6] += r1.z; acc[rr][7] += r1.w;
      }
    }
  }
  if (g == 0) {    // ty in {0,1}: k = (ty&1)*8 + rr
    #pragma unroll
    for (int cc = 0; cc < 8; ++cc) {
      int t = tx*8 + cc;
      f32x4 o0 = { acc[0][cc], acc[1][cc], acc[2][cc], acc[3][cc] };
      f32x4 o1 = { acc[4][cc], acc[5][cc], acc[6][cc], acc[7][cc] };
      size_t base = ((size_t)hh*BB + n)*1024 + t*16 + (ty & 1)*8;
      *(f32x4*)&part[base]     = o0;
      *(f32x4*)&part[base + 4] = o1;
    }
  }
}

// ---------------------------------------------------------------------------
// Combine the two h-half partials -> alpha_pi[t][n][k].
// ---------------------------------------------------------------------------
__global__ __launch_bounds__(256) void k_combine(
    const float* __restrict__ part, float* __restrict__ alphapi)
{
  int idx4 = blockIdx.x*256 + threadIdx.x;   // 262144
  size_t e = (size_t)idx4*4;
  int t = (int)(e >> 14);
  int n = (int)((e >> 4) & 1023);
  int k = (int)(e & 15);
  size_t po = (size_t)n*1024 + t*16 + k;
  f32x4 a = *(const f32x4*)&part[po];
  f32x4 b = *(const f32x4*)&part[(size_t)BB*1024 + po];
  f32x4 o = a + b;
  *(f32x4*)&alphapi[e] = o;
}

// ---------------------------------------------------------------------------
extern "C" void kernel_launch(void* const* d_in, const int* in_sizes, int n_in,
                              void* d_out, int out_size, void* d_ws, size_t ws_size,
                              hipStream_t stream) {
  const float* logp_o = (const float*)d_in[0];
  const float* u      = (const float*)d_in[1];
  const float* value  = (const float*)d_in[2];
  const float* b      = (const float*)d_in[3];
  const float* tau_p  = (const float*)d_in[4];
  const float* pu     = (const float*)d_in[5];
  const float* pv     = (const float*)d_in[6];
  const float* pw     = (const float*)d_in[7];

  float* alphab  = (float*)d_out;                       // [64][1024][256]
  float* alphapi = (float*)d_out + (size_t)TT*BB*SS;    // [64][1024][16]

  char* ws = (char*)d_ws;
  ushortT* tct  = (ushortT*)ws;                 ws += (size_t)4096*256*2;   // 2MB
  ushortT* belb = (ushortT*)ws;                 ws += (size_t)BB*SS*2;      // 512KB
  float*   Sn   = (float*)ws;                   ws += (size_t)BB*SS*4;      // 1MB
  float*   taupdf = (float*)ws;                 ws += 256;
  float*   part = (float*)ws;                                               // 8MB

  k_trans<<<AA*SS, 256, 0, stream>>>(pu, pv, pw, tct);
  k_tau<<<1, 64, 0, stream>>>(tau_p, taupdf);
  k_cvt<<<256, 256, 0, stream>>>(b, belb);

  for (int t = 0; t < TT; ++t) {
    k_step_gemm<<<dim3(16,32), 256, 0, stream>>>(belb, tct, u + (size_t)t*BB*AA, Sn);
    k_step_softmax<<<256, 256, 0, stream>>>(Sn, logp_o + (size_t)t*BB*SS,
                                            alphab + (size_t)t*BB*SS, belb);
  }
  k_phase2<<<2048, 256, 0, stream>>>(value, alphab, taupdf, part);
  k_combine<<<1024, 256, 0, stream>>>(part, alphapi);
}